// Round 5
// baseline (488.098 us; speedup 1.0000x reference)
//
#include <hip/hip_runtime.h>

// GAT on MI355X. Pipeline (5 kernels + 1 memset):
//  M0 memset       : cnt, a_src, a_dst = 0 (one contiguous region)
//  K1 gemm_att_deg : xh_bf = bf16(x @ lin_w.T); epilogue computes a_src/a_dst
//                    from f32 accumulators (shuffle-reduce + atomicAdd);
//                    degree histogram cnt[dst]++ issued at kernel start
//  K2 scan         : rowptr = exclusive prefix(cnt + 1 self-loop); wpos = copy
//  K3 scatter      : CSR bucket edges (+self loops) by dst + per-edge 8-head
//                    exp(leakyrelu) weights (computed once per edge)
//  K4 agg_dot      : per dst node: softmax-weighted gather of xh_bf[src] ->
//                    of row (regs->LDS) -> fused dot with out_w[:, i*256..]
//                    (268 MB nt float4 stream overlapped with gather latency)
//  K5 finalize     : reduce part[8192][32] + out_b + softmax -> d_out[32]

namespace {
constexpr int  kN    = 8192;
constexpr int  kE    = 262144;
constexpr int  kTotE = kE + kN;          // 270336 (self loops appended)
constexpr long kK    = 2097152;          // N * H * C
}

typedef float vfloat4 __attribute__((ext_vector_type(4)));  // native vec for nt loads

static __device__ __forceinline__ ushort f2bf(float f) {  // RNE f32->bf16
  unsigned u = __float_as_uint(f);
  return (ushort)((u + 0x7FFFu + ((u >> 16) & 1u)) >> 16);
}
static __device__ __forceinline__ float bf2f(ushort b) {
  return __uint_as_float(((unsigned)b) << 16);
}

// ------- K1: xh_bf = bf16(x @ lin_w^T) + attention dots + degree histogram -------
__global__ __launch_bounds__(256) void gemm_att_deg(const float* __restrict__ x,
                                                    const float* __restrict__ lw,
                                                    const float* __restrict__ att_s,
                                                    const float* __restrict__ att_d,
                                                    const int* __restrict__ ei,
                                                    ushort* __restrict__ xh_bf,
                                                    float* __restrict__ a_src,
                                                    float* __restrict__ a_dst,
                                                    int* __restrict__ cnt) {
  __shared__ float As[16][68];
  __shared__ float Bs[16][68];
  const int t  = threadIdx.x;
  const int tx = t & 15, ty = t >> 4;
  const int rowBase = blockIdx.x * 64;
  const int colBase = blockIdx.y * 64;
  const int lr = t >> 2;
  const int lk = (t & 3) * 4;

  // degree side-work first: atomics drain while the K-loop computes
  {
    const int gid = (blockIdx.y * 128 + blockIdx.x) * 256 + t;  // 0..131071
    atomicAdd(&cnt[ei[kE + gid]], 1);
    atomicAdd(&cnt[ei[kE + gid + 131072]], 1);
  }

  float acc[4][4] = {};
  for (int kc = 0; kc < 256; kc += 16) {
    float4 av = *(const float4*)(x  + (long)(rowBase + lr) * 256 + kc + lk);
    float4 bv = *(const float4*)(lw + (long)(colBase + lr) * 256 + kc + lk);
    __syncthreads();
    As[lk + 0][lr] = av.x; As[lk + 1][lr] = av.y; As[lk + 2][lr] = av.z; As[lk + 3][lr] = av.w;
    Bs[lk + 0][lr] = bv.x; Bs[lk + 1][lr] = bv.y; Bs[lk + 2][lr] = bv.z; Bs[lk + 3][lr] = bv.w;
    __syncthreads();
#pragma unroll
    for (int k = 0; k < 16; k++) {
      float4 a4 = *(const float4*)(&As[k][ty * 4]);
      float4 b4 = *(const float4*)(&Bs[k][tx * 4]);
      float aa[4] = {a4.x, a4.y, a4.z, a4.w};
      float bb[4] = {b4.x, b4.y, b4.z, b4.w};
#pragma unroll
      for (int i = 0; i < 4; i++)
#pragma unroll
        for (int j = 0; j < 4; j++) acc[i][j] += aa[i] * bb[j];
    }
  }

  // bf16 tile store
#pragma unroll
  for (int i = 0; i < 4; i++) {
    const long row = rowBase + ty * 4 + i;
    ushort4 ob = make_ushort4(f2bf(acc[i][0]), f2bf(acc[i][1]),
                              f2bf(acc[i][2]), f2bf(acc[i][3]));
    *(ushort4*)(xh_bf + row * 256 + colBase + tx * 4) = ob;
  }

  // attention epilogue: per-thread partial dot over its 4 cols, then
  // shuffle-reduce over the 8-lane tx half-groups (one head = 8 tx values)
  const int c0 = colBase + tx * 4;
  const int h  = (c0 >> 5) & 7;
  float as_c[4], ad_c[4];
#pragma unroll
  for (int j = 0; j < 4; j++) { as_c[j] = att_s[c0 + j]; ad_c[j] = att_d[c0 + j]; }
#pragma unroll
  for (int i = 0; i < 4; i++) {
    float ps = acc[i][0] * as_c[0] + acc[i][1] * as_c[1] +
               acc[i][2] * as_c[2] + acc[i][3] * as_c[3];
    float pd = acc[i][0] * ad_c[0] + acc[i][1] * ad_c[1] +
               acc[i][2] * ad_c[2] + acc[i][3] * ad_c[3];
    ps += __shfl_down(ps, 1, 64); ps += __shfl_down(ps, 2, 64); ps += __shfl_down(ps, 4, 64);
    pd += __shfl_down(pd, 1, 64); pd += __shfl_down(pd, 2, 64); pd += __shfl_down(pd, 4, 64);
    if ((tx & 7) == 0) {   // lanes tx=0 and tx=8 hold their 8-group sums
      const int row = rowBase + ty * 4 + i;
      atomicAdd(&a_src[row * 8 + h], ps);
      atomicAdd(&a_dst[row * 8 + h], pd);
    }
  }
}

// ---------------- K2: single-block exclusive scan (+1 self-loop each) ----------------
__global__ __launch_bounds__(1024) void scan_cnt(const int* __restrict__ cnt,
                                                 int* __restrict__ rowptr,
                                                 int* __restrict__ wpos) {
  __shared__ int s[1024];
  const int t = threadIdx.x;
  int v[8]; int sum = 0;
#pragma unroll
  for (int q = 0; q < 8; q++) { v[q] = cnt[t * 8 + q] + 1; sum += v[q]; }  // +1 self-loop
  s[t] = sum;
  __syncthreads();
  for (int off = 1; off < 1024; off <<= 1) {
    int add = (t >= off) ? s[t - off] : 0;
    __syncthreads();
    s[t] += add;
    __syncthreads();
  }
  int excl = s[t] - sum;
#pragma unroll
  for (int q = 0; q < 8; q++) {
    rowptr[t * 8 + q] = excl;
    wpos[t * 8 + q]   = excl;
    excl += v[q];
  }
  if (t == 1023) rowptr[kN] = s[1023];
}

// ---------------- K3: bucket edges by dst + per-edge 8-head weights ----------------
__global__ __launch_bounds__(256) void scatter_csr(const int* __restrict__ ei,
                                                   const float* __restrict__ a_src,
                                                   const float* __restrict__ a_dst,
                                                   int* __restrict__ wpos,
                                                   int* __restrict__ csr,
                                                   float* __restrict__ w8) {
  int idx = blockIdx.x * 256 + threadIdx.x;
  if (idx >= kTotE) return;
  int s, d;
  if (idx < kE) { s = ei[idx]; d = ei[kE + idx]; }
  else          { s = idx - kE; d = s; }
  int pos = atomicAdd(&wpos[d], 1);
  csr[pos] = s;
  float4 s0 = *(const float4*)(a_src + s * 8);
  float4 s1 = *(const float4*)(a_src + s * 8 + 4);
  float4 d0 = *(const float4*)(a_dst + d * 8);
  float4 d1 = *(const float4*)(a_dst + d * 8 + 4);
  float e[8] = {s0.x + d0.x, s0.y + d0.y, s0.z + d0.z, s0.w + d0.w,
                s1.x + d1.x, s1.y + d1.y, s1.z + d1.z, s1.w + d1.w};
  float w[8];
#pragma unroll
  for (int h = 0; h < 8; h++) {
    float ee = (e[h] > 0.f) ? e[h] : 0.2f * e[h];   // leaky_relu(0.2)
    w[h] = __expf(ee);                              // |e| <~ 5, no max-sub needed
  }
  float4* wp = (float4*)(w8 + (long)pos * 8);
  wp[0] = make_float4(w[0], w[1], w[2], w[3]);
  wp[1] = make_float4(w[4], w[5], w[6], w[7]);
}

// ------ K4: gather aggregation (bf16, unroll x8) fused with out_w dot stream ------
__global__ __launch_bounds__(256) void agg_dot(const ushort* __restrict__ xb,
                                               const float* __restrict__ w8,
                                               const int* __restrict__ rowptr,
                                               const int* __restrict__ csr,
                                               const float* __restrict__ bias,
                                               const float* __restrict__ w,
                                               float* __restrict__ part) {
  const int i = blockIdx.x, t = threadIdx.x, h = t >> 5;
  const int beg = rowptr[i], end = rowptr[i + 1];
  float acc = 0.f, den = 0.f;
  int j = beg;
  for (; j + 8 <= end; j += 8) {
    int s[8]; float ww[8]; float f[8];
#pragma unroll
    for (int q = 0; q < 8; q++) s[q] = csr[j + q];
#pragma unroll
    for (int q = 0; q < 8; q++) ww[q] = w8[(long)(j + q) * 8 + h];
#pragma unroll
    for (int q = 0; q < 8; q++) f[q] = bf2f(xb[(long)s[q] * 256 + t]);
#pragma unroll
    for (int q = 0; q < 8; q++) { den += ww[q]; acc += ww[q] * f[q]; }
  }
  for (; j < end; j++) {
    int s0 = csr[j];
    float w0 = w8[(long)j * 8 + h];
    den += w0;
    acc += w0 * bf2f(xb[(long)s0 * 256 + t]);
  }
  __shared__ float s_of[256];
  s_of[t] = acc / den + bias[t];
  __syncthreads();

  // fused final-dot: wave w4 = t>>6 handles c in {w4, w4+4, ..., w4+28};
  // lane q covers of elements q*4..q*4+3 (float4), 1 KB/wave per nt load
  const int q = t & 63, w4 = t >> 6;
  float4 fv = *(const float4*)(s_of + q * 4);
  float pr[8];
#pragma unroll
  for (int m = 0; m < 8; m++) {
    const int c = w4 + m * 4;
    vfloat4 wv = __builtin_nontemporal_load(
        (const vfloat4*)(w + (long)c * kK + (long)i * 256 + q * 4));
    pr[m] = wv.x * fv.x + wv.y * fv.y + wv.z * fv.z + wv.w * fv.w;
  }
#pragma unroll
  for (int m = 0; m < 8; m++) {
    float v = pr[m];
    v += __shfl_down(v, 32, 64);
    v += __shfl_down(v, 16, 64);
    v += __shfl_down(v, 8, 64);
    v += __shfl_down(v, 4, 64);
    v += __shfl_down(v, 2, 64);
    v += __shfl_down(v, 1, 64);
    if (q == 0) part[(long)i * 32 + w4 + m * 4] = v;
  }
}

// ---------------- K5: reduce part[8192][32] + bias + softmax ----------------
__global__ __launch_bounds__(1024) void finalize(const float* __restrict__ part,
                                                 const float* __restrict__ ob,
                                                 float* __restrict__ out) {
  __shared__ float s[32][33];
  const int t = threadIdx.x;
  const int c = t & 31, r = t >> 5;
  float sum = 0.f;
  for (int i = r; i < kN; i += 32) sum += part[(long)i * 32 + c];
  s[c][r] = sum;
  __syncthreads();
  if (t < 32) {
    float y = ob[t];
#pragma unroll
    for (int r2 = 0; r2 < 32; r2++) y += s[t][r2];
    float m = y;
#pragma unroll
    for (int off = 16; off; off >>= 1) m = fmaxf(m, __shfl_xor(m, off, 32));
    float e = __expf(y - m);
    float d = e;
#pragma unroll
    for (int off = 16; off; off >>= 1) d += __shfl_xor(d, off, 32);
    out[t] = e / d;
  }
}

extern "C" void kernel_launch(void* const* d_in, const int* in_sizes, int n_in,
                              void* d_out, int out_size, void* d_ws, size_t ws_size,
                              hipStream_t stream) {
  (void)in_sizes; (void)n_in; (void)out_size; (void)ws_size;
  const float* x     = (const float*)d_in[0];
  const int*   ei    = (const int*)  d_in[1];
  const float* lin_w = (const float*)d_in[2];
  const float* att_s = (const float*)d_in[3];
  const float* att_d = (const float*)d_in[4];
  const float* bias  = (const float*)d_in[5];
  const float* out_w = (const float*)d_in[6];
  const float* out_b = (const float*)d_in[7];
  float* out = (float*)d_out;

  // workspace layout (~15.5 MB); [cnt|a_src|a_dst] contiguous -> one memset
  int*    cnt    = (int*)d_ws;
  float*  a_src  = (float*)(cnt + kN);
  float*  a_dst  = a_src + kN * 8;
  ushort* xh_bf  = (ushort*)(a_dst + kN * 8);
  float*  w8     = (float*)(xh_bf + kK);
  float*  part   = w8 + (long)kTotE * 8;
  int*    rowptr = (int*)(part + (long)kN * 32);
  int*    wpos   = rowptr + (kN + 1);
  int*    csr    = wpos + kN;

  (void)hipMemsetAsync(cnt, 0, (kN + 2 * kN * 8) * sizeof(int), stream);
  gemm_att_deg<<<dim3(128, 4), 256, 0, stream>>>(x, lin_w, att_s, att_d, ei,
                                                 xh_bf, a_src, a_dst, cnt);
  scan_cnt    <<<1, 1024, 0, stream>>>(cnt, rowptr, wpos);
  scatter_csr <<<kTotE / 256, 256, 0, stream>>>(ei, a_src, a_dst, wpos, csr, w8);
  agg_dot     <<<kN, 256, 0, stream>>>(xh_bf, w8, rowptr, csr, bias, out_w, part);
  finalize    <<<1, 1024, 0, stream>>>(part, out_b, out);
}